// Round 1
// baseline (248.435 us; speedup 1.0000x reference)
//
#include <hip/hip_runtime.h>

typedef __attribute__((ext_vector_type(4))) float f4;

#define NK 64
#define NC 128
#define NP 4096
#define NN 32
#define EPSV 1e-12f
#define PT 64
#define ROWP 68

// ws layout (floats)
#define WS_VLAD 0
#define WS_S    (NN * NK * NC)          // 262144
#define WS_G    (WS_S + NN * NK)        // +2048
#define WS_TOTAL (WS_G + NN)            // +32

__global__ void nv_zero(float* __restrict__ ws) {
  int i = blockIdx.x * blockDim.x + threadIdx.x;
  int stride = gridDim.x * blockDim.x;
  for (; i < WS_TOTAL; i += stride) ws[i] = 0.0f;
}

// Fused: x-normalize + 1x1 conv (logits) + softmax + vlad partial accumulation.
// Grid: (16 position-chunks, 32 images). Block: 256 threads.
__global__ __launch_bounds__(256, 1)
void nv_main(const float* __restrict__ x, const float* __restrict__ conv_w,
             const float* __restrict__ conv_b, float* __restrict__ vlad_acc,
             float* __restrict__ s_acc) {
  __shared__ __align__(16) float Wt[NC][ROWP];   // Wt[c][k] = conv_w[k][c]
  __shared__ __align__(16) float Xs[NC][ROWP];   // raw x tile, XOR-swizzled rows
  __shared__ __align__(16) float At[PT][ROWP];   // logits, then a*inv  [p][k]
  __shared__ float inv_lds[PT];

  const int tid = threadIdx.x;
  const int n = blockIdx.y;
  const int p0 = blockIdx.x * 256;

  const int tk = tid & 15;   // k-group: k4 = 4*tk
  const int tg = tid >> 4;   // p-group (logits) / c-group (vlad)
  const int k4 = tk << 2;
  const int p4 = tg << 2;
  const int c8 = tg << 3;

  // stage W transposed (coalesced global read)
  for (int idx = tid; idx < NK * NC; idx += 256) {
    int k = idx >> 7;
    int c = idx & 127;
    Wt[c][k] = conv_w[idx];
  }
  float breg[4];
#pragma unroll
  for (int i = 0; i < 4; ++i) breg[i] = conv_b[k4 + i];

  float acc[4][8];
#pragma unroll
  for (int i = 0; i < 4; ++i)
#pragma unroll
    for (int r = 0; r < 8; ++r) acc[i][r] = 0.0f;
  float s_part[16];
#pragma unroll
  for (int i = 0; i < 16; ++i) s_part[i] = 0.0f;

  const float* xb = x + (size_t)n * NC * NP + p0;

  for (int st = 0; st < 4; ++st) {
    __syncthreads();  // protect Xs/At from previous subtile's readers
    // ---- stage Xs (swizzled: word = c*ROWP + (p ^ (((c>>3)&3)<<2)) ) ----
    const float* xsub = xb + st * PT;
    for (int q = tid; q < NC * PT / 4; q += 256) {
      int c = q >> 4;
      int pq = (q & 15) << 2;
      f4 v = *reinterpret_cast<const f4*>(xsub + (size_t)c * NP + pq);
      int sw = (c >> 3) & 3;
      *reinterpret_cast<f4*>(&Xs[c][pq ^ (sw << 2)]) = v;
    }
    __syncthreads();
    // ---- per-position inverse norms (4 lanes per position) ----
    {
      int sub = tid & 3;
      int pl = tid >> 2;
      float ss = 0.0f;
#pragma unroll
      for (int cc = 0; cc < 32; ++cc) {
        int c = (sub << 5) + cc;
        int sw = (c >> 3) & 3;
        float v = Xs[c][pl ^ (sw << 2)];
        ss += v * v;
      }
      ss += __shfl_xor(ss, 1);
      ss += __shfl_xor(ss, 2);
      if (sub == 0) inv_lds[pl] = 1.0f / fmaxf(sqrtf(ss), EPSV);
    }
    __syncthreads();
    // ---- logits: 4k x 4p per thread, fp32 dot over C ----
    float dot[4][4];
#pragma unroll
    for (int i = 0; i < 4; ++i)
#pragma unroll
      for (int j = 0; j < 4; ++j) dot[i][j] = 0.0f;
    for (int c = 0; c < NC; ++c) {
      f4 wf = *reinterpret_cast<const f4*>(&Wt[c][k4]);
      int sw = (c >> 3) & 3;
      f4 xf = *reinterpret_cast<const f4*>(&Xs[c][p4 ^ (sw << 2)]);
#pragma unroll
      for (int i = 0; i < 4; ++i)
#pragma unroll
        for (int j = 0; j < 4; ++j) dot[i][j] += wf[i] * xf[j];
    }
#pragma unroll
    for (int j = 0; j < 4; ++j) {
      float iv = inv_lds[p4 + j];
      f4 lv;
#pragma unroll
      for (int i = 0; i < 4; ++i) lv[i] = dot[i][j] * iv + breg[i];
      *reinterpret_cast<f4*>(&At[p4 + j][k4]) = lv;
    }
    __syncthreads();
    // ---- softmax over k per position; store a*inv; accumulate S in regs ----
    {
      int sub = tid & 3;
      int pl = tid >> 2;
      f4 lv[4];
#pragma unroll
      for (int m = 0; m < 4; ++m)
        lv[m] = *reinterpret_cast<const f4*>(&At[pl][(sub << 4) + (m << 2)]);
      float mx = lv[0][0];
#pragma unroll
      for (int m = 0; m < 4; ++m)
#pragma unroll
        for (int j = 0; j < 4; ++j) mx = fmaxf(mx, lv[m][j]);
      mx = fmaxf(mx, __shfl_xor(mx, 1));
      mx = fmaxf(mx, __shfl_xor(mx, 2));
      float sum = 0.0f;
#pragma unroll
      for (int m = 0; m < 4; ++m)
#pragma unroll
        for (int j = 0; j < 4; ++j) {
          float e = __expf(lv[m][j] - mx);
          lv[m][j] = e;
          sum += e;
        }
      sum += __shfl_xor(sum, 1);
      sum += __shfl_xor(sum, 2);
      float rs = 1.0f / sum;
      float ivp = inv_lds[pl];
#pragma unroll
      for (int m = 0; m < 4; ++m)
#pragma unroll
        for (int j = 0; j < 4; ++j) {
          float a = lv[m][j] * rs;
          s_part[(m << 2) + j] += a;   // S uses plain a
          lv[m][j] = a * ivp;          // vlad uses a*inv (raw x reused)
        }
#pragma unroll
      for (int m = 0; m < 4; ++m)
        *reinterpret_cast<f4*>(&At[pl][(sub << 4) + (m << 2)]) = lv[m];
    }
    __syncthreads();
    // ---- vlad partial: acc[4k][8c] += A[k][p] * X[c][p], 4 p per step ----
    for (int p = 0; p < PT; p += 4) {
      f4 a0 = *reinterpret_cast<const f4*>(&At[p + 0][k4]);
      f4 a1 = *reinterpret_cast<const f4*>(&At[p + 1][k4]);
      f4 a2 = *reinterpret_cast<const f4*>(&At[p + 2][k4]);
      f4 a3 = *reinterpret_cast<const f4*>(&At[p + 3][k4]);
#pragma unroll
      for (int r = 0; r < 8; ++r) {
        int c = c8 + r;
        int sw = (c >> 3) & 3;
        f4 xv = *reinterpret_cast<const f4*>(&Xs[c][p ^ (sw << 2)]);
#pragma unroll
        for (int i = 0; i < 4; ++i)
          acc[i][r] += a0[i] * xv[0] + a1[i] * xv[1] + a2[i] * xv[2] + a3[i] * xv[3];
      }
    }
  }

  // S reduction across lanes sharing (tid&3), then one atomic per (wave,sub,k)
#pragma unroll
  for (int off = 4; off < 64; off <<= 1)
#pragma unroll
    for (int i = 0; i < 16; ++i) s_part[i] += __shfl_xor(s_part[i], off);
  if ((tid & 63) < 4) {
    int sub = tid & 3;
#pragma unroll
    for (int i = 0; i < 16; ++i)
      atomicAdd(&s_acc[n * NK + (sub << 4) + i], s_part[i]);
  }

#pragma unroll
  for (int i = 0; i < 4; ++i)
#pragma unroll
    for (int r = 0; r < 8; ++r)
      atomicAdd(&vlad_acc[((size_t)n * NK + k4 + i) * NC + c8 + r], acc[i][r]);
}

// Per (n,k): subtract S*centroid, intra-normalize over C, accumulate global sumsq.
__global__ void nv_finalize(const float* __restrict__ vlad_acc,
                            const float* __restrict__ s_acc,
                            const float* __restrict__ centroids,
                            float* __restrict__ out, float* __restrict__ gnorm) {
  const int k = blockIdx.x;
  const int n = blockIdx.y;
  const int t = threadIdx.x;  // 64 threads
  const float s = s_acc[n * NK + k];
  const size_t base = ((size_t)n * NK + k) * NC;
  float v0 = vlad_acc[base + t] - s * centroids[k * NC + t];
  float v1 = vlad_acc[base + t + 64] - s * centroids[k * NC + t + 64];
  float ss = v0 * v0 + v1 * v1;
#pragma unroll
  for (int off = 1; off < 64; off <<= 1) ss += __shfl_xor(ss, off);
  float inv = 1.0f / fmaxf(sqrtf(ss), EPSV);
  out[base + t] = v0 * inv;
  out[base + t + 64] = v1 * inv;
  if (t == 0) atomicAdd(&gnorm[n], ss * inv * inv);
}

__global__ void nv_scale(float* __restrict__ out, const float* __restrict__ gnorm) {
  int i = blockIdx.x * blockDim.x + threadIdx.x;  // 262144 elements
  int n = i >> 13;
  out[i] *= 1.0f / fmaxf(sqrtf(gnorm[n]), EPSV);
}

extern "C" void kernel_launch(void* const* d_in, const int* in_sizes, int n_in,
                              void* d_out, int out_size, void* d_ws, size_t ws_size,
                              hipStream_t stream) {
  const float* x = (const float*)d_in[0];
  const float* conv_w = (const float*)d_in[1];
  const float* conv_b = (const float*)d_in[2];
  const float* centroids = (const float*)d_in[3];
  float* out = (float*)d_out;
  float* ws = (float*)d_ws;
  float* vlad_acc = ws + WS_VLAD;
  float* s_acc = ws + WS_S;
  float* gnorm = ws + WS_G;

  nv_zero<<<256, 256, 0, stream>>>(ws);
  nv_main<<<dim3(16, NN), 256, 0, stream>>>(x, conv_w, conv_b, vlad_acc, s_acc);
  nv_finalize<<<dim3(NK, NN), 64, 0, stream>>>(vlad_acc, s_acc, centroids, out, gnorm);
  nv_scale<<<1024, 256, 0, stream>>>(out, gnorm);
}

// Round 2
// 209.221 us; speedup vs baseline: 1.1874x; 1.1874x over previous
//
#include <hip/hip_runtime.h>

typedef __attribute__((ext_vector_type(4))) float f4;
typedef __attribute__((ext_vector_type(4))) float f32x4;
typedef __attribute__((ext_vector_type(8))) short bf16x8;

#define NK 64
#define NC 128
#define NP 4096
#define NN 32
#define EPSV 1e-12f

#define PCH 64                 // positions per chunk
#define CPB 2                  // chunks per block
#define NGRPX ((NP / PCH) / CPB)  // 32 -> grid.x

#define XP 72                  // xh/xl row pitch in bf16 (144 B, 16B-aligned rows)
#define LP 68                  // L row pitch in f32 (272 B, 16B-aligned rows)

// ws layout (floats)
#define WS_VLAD 0
#define WS_S    (NN * NK * NC)          // 262144
#define WS_G    (WS_S + NN * NK)        // +2048
#define WS_TOTAL (WS_G + NN)            // +32

__device__ __forceinline__ unsigned short f2bf(float x) {
  unsigned u = __builtin_bit_cast(unsigned, x);
  u += 0x7fffu + ((u >> 16) & 1u);      // RTNE
  return (unsigned short)(u >> 16);
}
__device__ __forceinline__ float bf2f(unsigned short h) {
  unsigned u = ((unsigned)h) << 16;
  return __builtin_bit_cast(float, u);
}

__global__ void nv_zero(float* __restrict__ ws) {
  int i = blockIdx.x * blockDim.x + threadIdx.x;
  int stride = gridDim.x * blockDim.x;
  for (; i < WS_TOTAL; i += stride) ws[i] = 0.0f;
}

// Fused: stage split-bf16 x -> norms -> MFMA logits -> softmax -> MFMA vlad partial.
// Grid (32 pgroups, 32 n), 256 threads (4 waves; wave w owns k-tile w).
__global__ __launch_bounds__(256, 3)
void nv_main(const float* __restrict__ x, const float* __restrict__ conv_w,
             const float* __restrict__ conv_b, float* __restrict__ vlad_acc,
             float* __restrict__ s_acc) {
  __shared__ unsigned short xh[NC][XP];   // 18432 B, col index swizzled: p ^ (((c>>3)&3)<<3)
  __shared__ unsigned short xl[NC][XP];   // 18432 B
  __shared__ float L[NK][LP];             // 17408 B; later low-halves reused as bf16 A
  __shared__ float inv_lds[PCH];          // 256 B   (total 54528 B -> 3 blocks/CU)

  const int tid = threadIdx.x;
  const int lane = tid & 63;
  const int wv = tid >> 6;      // wave id == k-tile
  const int r = lane & 15;
  const int g = lane >> 4;
  const int n = blockIdx.y;
  const int k0 = wv << 4;

  // ---- W fragments (hi/lo) resident in registers: A-frag lane holds W[k0+r][32ct+8g+j] ----
  bf16x8 whf[4], wlf[4];
#pragma unroll
  for (int ct = 0; ct < 4; ++ct) {
    const float* wsrc = conv_w + (k0 + r) * NC + ct * 32 + g * 8;
    f4 va = *(const f4*)wsrc;
    f4 vb = *(const f4*)(wsrc + 4);
#pragma unroll
    for (int j = 0; j < 8; ++j) {
      float v = (j < 4) ? va[j] : vb[j - 4];
      unsigned short h = f2bf(v);
      unsigned short lo = f2bf(v - bf2f(h));
      whf[ct][j] = (short)h;
      wlf[ct][j] = (short)lo;
    }
  }
  float breg[4];
#pragma unroll
  for (int i = 0; i < 4; ++i) breg[i] = conv_b[k0 + 4 * g + i];

  f32x4 vacc[8];
#pragma unroll
  for (int t = 0; t < 8; ++t) vacc[t] = (f32x4){0.f, 0.f, 0.f, 0.f};
  float s_part[16];
#pragma unroll
  for (int i = 0; i < 16; ++i) s_part[i] = 0.f;

  const int cstage = tid >> 1;            // staging row
  const int pstage = (tid & 1) << 5;      // 0 / 32
  const int swst = ((cstage >> 3) & 3) << 3;
  const int ssm = tid & 3;                // norm/softmax sub-lane
  const int psm = tid >> 2;               // norm/softmax position

  for (int cc = 0; cc < CPB; ++cc) {
    const int p0 = (blockIdx.x * CPB + cc) * PCH;
    const float* xb = x + ((size_t)n * NC + cstage) * NP + p0 + pstage;
    __syncthreads();  // protect xh/xl/L from previous chunk's readers
    // ---- stage: fp32 -> bf16 hi/lo, swizzled packed writes ----
#pragma unroll
    for (int q4 = 0; q4 < 8; ++q4) {
      f4 v = *(const f4*)(xb + q4 * 4);
      int pp = (pstage + q4 * 4) ^ swst;
      unsigned hh0, hh1, ll0, ll1;
      {
        unsigned short h0 = f2bf(v[0]), h1 = f2bf(v[1]), h2 = f2bf(v[2]), h3 = f2bf(v[3]);
        unsigned short l0 = f2bf(v[0] - bf2f(h0)), l1 = f2bf(v[1] - bf2f(h1));
        unsigned short l2 = f2bf(v[2] - bf2f(h2)), l3 = f2bf(v[3] - bf2f(h3));
        hh0 = (unsigned)h0 | ((unsigned)h1 << 16);
        hh1 = (unsigned)h2 | ((unsigned)h3 << 16);
        ll0 = (unsigned)l0 | ((unsigned)l1 << 16);
        ll1 = (unsigned)l2 | ((unsigned)l3 << 16);
      }
      *(unsigned*)&xh[cstage][pp] = hh0;
      *(unsigned*)&xh[cstage][pp + 2] = hh1;
      *(unsigned*)&xl[cstage][pp] = ll0;
      *(unsigned*)&xl[cstage][pp + 2] = ll1;
    }
    __syncthreads();
    // ---- per-position inverse norms (4 lanes/position, from hi+lo = full precision) ----
    {
      float ssum = 0.0f;
#pragma unroll
      for (int ci = 0; ci < 32; ++ci) {
        int c = (ssm << 5) + ci;
        int pp = psm ^ (((c >> 3) & 3) << 3);
        float xv = bf2f(xh[c][pp]) + bf2f(xl[c][pp]);
        ssum += xv * xv;
      }
      ssum += __shfl_xor(ssum, 1);
      ssum += __shfl_xor(ssum, 2);
      if (ssm == 0) inv_lds[psm] = 1.0f / fmaxf(sqrtf(ssum), EPSV);
    }
    __syncthreads();
    // ---- logits: wave wv computes [16k x 64p] via 3-product split MFMA ----
#pragma unroll
    for (int pt = 0; pt < 4; ++pt) {
      f32x4 lacc = {0.f, 0.f, 0.f, 0.f};
      const int p = (pt << 4) + r;
      const int pp = p ^ (g << 3);
#pragma unroll
      for (int ct = 0; ct < 4; ++ct) {
        const int cb = (ct << 5) + (g << 3);
        bf16x8 bh, bl;
#pragma unroll
        for (int j = 0; j < 8; ++j) {
          bh[j] = (short)xh[cb + j][pp];
          bl[j] = (short)xl[cb + j][pp];
        }
        lacc = __builtin_amdgcn_mfma_f32_16x16x32_bf16(whf[ct], bh, lacc, 0, 0, 0);
        lacc = __builtin_amdgcn_mfma_f32_16x16x32_bf16(wlf[ct], bh, lacc, 0, 0, 0);
        lacc = __builtin_amdgcn_mfma_f32_16x16x32_bf16(whf[ct], bl, lacc, 0, 0, 0);
      }
      const float iv = inv_lds[p];
#pragma unroll
      for (int i = 0; i < 4; ++i)
        L[k0 + (g << 2) + i][p] = lacc[i] * iv + breg[i];
    }
    __syncthreads();
    // ---- softmax over k (4 lanes/position); write bf16(a*inv) in-place into L ----
    {
      float lv[16];
#pragma unroll
      for (int i = 0; i < 16; ++i) lv[i] = L[(ssm << 4) + i][psm];
      float mx = lv[0];
#pragma unroll
      for (int i = 1; i < 16; ++i) mx = fmaxf(mx, lv[i]);
      mx = fmaxf(mx, __shfl_xor(mx, 1));
      mx = fmaxf(mx, __shfl_xor(mx, 2));
      float sum = 0.f;
#pragma unroll
      for (int i = 0; i < 16; ++i) { lv[i] = __expf(lv[i] - mx); sum += lv[i]; }
      sum += __shfl_xor(sum, 1);
      sum += __shfl_xor(sum, 2);
      const float rs = 1.0f / sum;
      const float ivp = inv_lds[psm];
      unsigned short* arow = (unsigned short*)&L[0][0];  // bf16 view: idx = k*136 + p
#pragma unroll
      for (int i = 0; i < 16; ++i) {
        float a = lv[i] * rs;
        s_part[i] += a;                           // S uses plain a
        arow[((ssm << 4) + i) * 136 + psm] = f2bf(a * ivp);
      }
    }
    __syncthreads();
    // ---- vlad partial: wave wv owns [16k x 128c], contract 64 p (Ah*Xh only) ----
#pragma unroll
    for (int ps = 0; ps < 2; ++ps) {
      const unsigned short* lrow = (const unsigned short*)&L[0][0];
      bf16x8 af = *(const bf16x8*)(lrow + (k0 + r) * 136 + (ps << 5) + (g << 3));
#pragma unroll
      for (int tcl = 0; tcl < 8; ++tcl) {
        const int c = (tcl << 4) + r;
        const int pblk = ((ps << 2) + g) ^ ((c >> 3) & 3);
        bf16x8 bx = *(const bf16x8*)&xh[c][pblk << 3];
        vacc[tcl] = __builtin_amdgcn_mfma_f32_16x16x32_bf16(af, bx, vacc[tcl], 0, 0, 0);
      }
    }
  }

  // ---- S reduction (lanes sharing s=lane&3) + atomics ----
#pragma unroll
  for (int off = 4; off < 64; off <<= 1)
#pragma unroll
    for (int i = 0; i < 16; ++i) s_part[i] += __shfl_xor(s_part[i], off);
  if (lane < 4) {
#pragma unroll
    for (int i = 0; i < 16; ++i)
      atomicAdd(&s_acc[n * NK + (lane << 4) + i], s_part[i]);
  }
  // ---- vlad partial atomics: D row = k0+4g+i, col = 16*tcl + r ----
#pragma unroll
  for (int tcl = 0; tcl < 8; ++tcl)
#pragma unroll
    for (int i = 0; i < 4; ++i)
      atomicAdd(&vlad_acc[((size_t)n * NK + k0 + (g << 2) + i) * NC + (tcl << 4) + r],
                vacc[tcl][i]);
}

// Per (n,k): subtract S*centroid, intra-normalize over C, accumulate global sumsq.
__global__ void nv_finalize(const float* __restrict__ vlad_acc,
                            const float* __restrict__ s_acc,
                            const float* __restrict__ centroids,
                            float* __restrict__ out, float* __restrict__ gnorm) {
  const int k = blockIdx.x;
  const int n = blockIdx.y;
  const int t = threadIdx.x;  // 64 threads
  const float s = s_acc[n * NK + k];
  const size_t base = ((size_t)n * NK + k) * NC;
  float v0 = vlad_acc[base + t] - s * centroids[k * NC + t];
  float v1 = vlad_acc[base + t + 64] - s * centroids[k * NC + t + 64];
  float ss = v0 * v0 + v1 * v1;
#pragma unroll
  for (int off = 1; off < 64; off <<= 1) ss += __shfl_xor(ss, off);
  float inv = 1.0f / fmaxf(sqrtf(ss), EPSV);
  out[base + t] = v0 * inv;
  out[base + t + 64] = v1 * inv;
  if (t == 0) atomicAdd(&gnorm[n], ss * inv * inv);
}

__global__ void nv_scale(float* __restrict__ out, const float* __restrict__ gnorm) {
  int i = blockIdx.x * blockDim.x + threadIdx.x;  // 262144 elements
  int n = i >> 13;
  out[i] *= 1.0f / fmaxf(sqrtf(gnorm[n]), EPSV);
}

extern "C" void kernel_launch(void* const* d_in, const int* in_sizes, int n_in,
                              void* d_out, int out_size, void* d_ws, size_t ws_size,
                              hipStream_t stream) {
  const float* x = (const float*)d_in[0];
  const float* conv_w = (const float*)d_in[1];
  const float* conv_b = (const float*)d_in[2];
  const float* centroids = (const float*)d_in[3];
  float* out = (float*)d_out;
  float* ws = (float*)d_ws;
  float* vlad_acc = ws + WS_VLAD;
  float* s_acc = ws + WS_S;
  float* gnorm = ws + WS_G;

  nv_zero<<<256, 256, 0, stream>>>(ws);
  nv_main<<<dim3(NGRPX, NN), 256, 0, stream>>>(x, conv_w, conv_b, vlad_acc, s_acc);
  nv_finalize<<<dim3(NK, NN), 64, 0, stream>>>(vlad_acc, s_acc, centroids, out, gnorm);
  nv_scale<<<1024, 256, 0, stream>>>(out, gnorm);
}

// Round 3
// 82.051 us; speedup vs baseline: 3.0278x; 2.5499x over previous
//
#include <hip/hip_runtime.h>

typedef __attribute__((ext_vector_type(4))) float f4;
typedef __attribute__((ext_vector_type(4))) float f32x4;
typedef __attribute__((ext_vector_type(4))) unsigned u32x4;
typedef __attribute__((ext_vector_type(8))) short bf16x8;

#define NK 64
#define NC 128
#define NP 4096
#define NN 32
#define EPSV 1e-12f

#define PCH 64                     // positions per chunk
#define CPB 2                      // chunks per block
#define NGRPX ((NP / PCH) / CPB)   // 32 -> grid.x

// ws layout (floats)
#define WS_VLAD 0
#define WS_S    (NN * NK * NC)           // 262144
#define WS_G    (WS_S + NN * NK)         // +2048
#define WS_WF   (WS_G + NN)              // +32  (W frags: 2048 lane-slots * 8 bf16 = 8192 floats)
#define WS_TOTAL (WS_WF + 8192)

__device__ __forceinline__ unsigned short f2bf(float x) {
  unsigned u = __builtin_bit_cast(unsigned, x);
  u += 0x7fffu + ((u >> 16) & 1u);      // RTNE
  return (unsigned short)(u >> 16);
}
__device__ __forceinline__ float bf2f(unsigned short h) {
  unsigned u = ((unsigned)h) << 16;
  return __builtin_bit_cast(float, u);
}

__global__ void nv_zero(float* __restrict__ ws) {
  int i = blockIdx.x * blockDim.x + threadIdx.x;
  int stride = gridDim.x * blockDim.x;
  for (; i < WS_WF; i += stride) ws[i] = 0.0f;
}

// Precompute W fragments (hi/lo bf16) laid out per-lane for direct b128 loads.
// slot = ((kt*4 + ct)*2 + hl)*64 + lane ; elem j = conv_w[16kt+r][32ct+8g+j]
__global__ void nv_wfrag(const float* __restrict__ conv_w, unsigned short* __restrict__ wfrag) {
  int idx = blockIdx.x * 256 + threadIdx.x;   // 2048 lane-slots
  if (idx >= 2048) return;
  int lane = idx & 63, hl = (idx >> 6) & 1, ct = (idx >> 7) & 3, kt = idx >> 9;
  int r = lane & 15, g = lane >> 4;
  const float* src = conv_w + (16 * kt + r) * NC + 32 * ct + 8 * g;
  unsigned short o[8];
#pragma unroll
  for (int j = 0; j < 8; ++j) {
    float v = src[j];
    unsigned short h = f2bf(v);
    o[j] = hl ? f2bf(v - bf2f(h)) : h;
  }
  u32x4 pk;
#pragma unroll
  for (int m = 0; m < 4; ++m) pk[m] = (unsigned)o[2 * m] | ((unsigned)o[2 * m + 1] << 16);
  *reinterpret_cast<u32x4*>(wfrag + (size_t)idx * 8) = pk;
}

// Fused main kernel. Grid (32, 32), 256 threads (4 waves; wave wv owns p-rows 16wv..+15
// for logits/softmax, and k-tile wv for vlad).
__global__ __launch_bounds__(256, 2)
void nv_main(const float* __restrict__ x, const unsigned short* __restrict__ wfrag,
             const float* __restrict__ conv_b, float* __restrict__ vlad_acc,
             float* __restrict__ s_acc) {
  __shared__ __align__(16) unsigned xhl_t[PCH][132];        // [p][c] u32 = hi<<16|lo  (33792 B)
  __shared__ __align__(16) unsigned short xh[NC][72];       // [c][p^swz] hi           (18432 B)
  __shared__ __align__(16) unsigned short a_lds[NK][72];    // [k][p] bf16(a*inv)      (9216 B)
  __shared__ __align__(16) float inv_lds[PCH];              //                         (256 B)

  const int tid = threadIdx.x;
  const int lane = tid & 63;
  const int wv = tid >> 6;
  const int r = lane & 15;
  const int g = lane >> 4;
  const int n = blockIdx.y;
  const int p0loc = wv << 4;      // logits p-rows for this wave
  const int k0 = wv << 4;         // vlad k-tile for this wave

  // ---- W fragments: 32 x b128 coalesced loads from precomputed ws ----
  bf16x8 wf[4][4][2];
#pragma unroll
  for (int kt = 0; kt < 4; ++kt)
#pragma unroll
    for (int ct = 0; ct < 4; ++ct)
#pragma unroll
      for (int hl = 0; hl < 2; ++hl)
        wf[kt][ct][hl] = *reinterpret_cast<const bf16x8*>(
            wfrag + ((((size_t)(kt * 4 + ct) * 2 + hl) * 64) + lane) * 8);
  float bb[4];
#pragma unroll
  for (int kt = 0; kt < 4; ++kt) bb[kt] = conv_b[16 * kt + r];

  f32x4 vacc[8];
#pragma unroll
  for (int t = 0; t < 8; ++t) vacc[t] = (f32x4){0.f, 0.f, 0.f, 0.f};
  float s_part[4] = {0.f, 0.f, 0.f, 0.f};

  const int cst = tid & 127;           // staging channel
  const int phst = tid >> 7;           // staging p-half (0/1)
  const int swst = ((cst >> 3) & 3) << 3;
  const int psm = tid >> 2;            // norm position
  const int ssm = tid & 3;             // norm sub-lane

  for (int cc = 0; cc < CPB; ++cc) {
    const int p0 = (blockIdx.x * CPB + cc) * PCH;
    __syncthreads();  // previous chunk fully consumed
    // ---- stage: fp32 -> (hi,lo) packed u32 into xhl_t[p][c]; hi pairs into xh[c][p^swz] ----
    {
      const float* xb = x + ((size_t)n * NC + cst) * NP + p0 + 32 * phst;
#pragma unroll
      for (int q4 = 0; q4 < 8; ++q4) {
        f4 v = *reinterpret_cast<const f4*>(xb + 4 * q4);
        const int pl = 32 * phst + 4 * q4;
        unsigned short h[4], l[4];
#pragma unroll
        for (int j = 0; j < 4; ++j) {
          h[j] = f2bf(v[j]);
          l[j] = f2bf(v[j] - bf2f(h[j]));
        }
        const int pp = pl ^ swst;
        *reinterpret_cast<unsigned*>(&xh[cst][pp]) = (unsigned)h[0] | ((unsigned)h[1] << 16);
        *reinterpret_cast<unsigned*>(&xh[cst][pp + 2]) = (unsigned)h[2] | ((unsigned)h[3] << 16);
#pragma unroll
        for (int j = 0; j < 4; ++j)
          xhl_t[pl + j][cst] = ((unsigned)h[j] << 16) | (unsigned)l[j];
      }
    }
    __syncthreads();
    // ---- per-position inverse norms (4 lanes/position, b128 reads, hi+lo precision) ----
    {
      float ss = 0.0f;
#pragma unroll
      for (int m = 0; m < 8; ++m) {
        u32x4 w = *reinterpret_cast<const u32x4*>(&xhl_t[psm][32 * ssm + 4 * m]);
#pragma unroll
        for (int e = 0; e < 4; ++e) {
          float hi = __builtin_bit_cast(float, w[e] & 0xffff0000u);
          float lo = __builtin_bit_cast(float, w[e] << 16);
          float f = hi + lo;
          ss += f * f;
        }
      }
      ss += __shfl_xor(ss, 1);
      ss += __shfl_xor(ss, 2);
      if (ssm == 0) inv_lds[psm] = 1.0f / fmaxf(sqrtf(ss), EPSV);
    }
    __syncthreads();
    // ---- logits (swapped: A = X^T from xhl_t, B = W regs). Wave owns 16 p, all 64 k. ----
    bf16x8 Ah[4], Al[4];
#pragma unroll
    for (int ct = 0; ct < 4; ++ct) {
      const unsigned* row = &xhl_t[p0loc + r][32 * ct + 8 * g];
      u32x4 wA = *reinterpret_cast<const u32x4*>(row);
      u32x4 wB = *reinterpret_cast<const u32x4*>(row + 4);
      unsigned wv8[8] = {wA[0], wA[1], wA[2], wA[3], wB[0], wB[1], wB[2], wB[3]};
      u32x4 hh, ll;
#pragma unroll
      for (int m = 0; m < 4; ++m) {
        hh[m] = __builtin_amdgcn_perm(wv8[2 * m + 1], wv8[2 * m], 0x07060302u);
        ll[m] = __builtin_amdgcn_perm(wv8[2 * m + 1], wv8[2 * m], 0x05040100u);
      }
      Ah[ct] = __builtin_bit_cast(bf16x8, hh);
      Al[ct] = __builtin_bit_cast(bf16x8, ll);
    }
    f32x4 lac[4];
#pragma unroll
    for (int kt = 0; kt < 4; ++kt) lac[kt] = (f32x4){0.f, 0.f, 0.f, 0.f};
#pragma unroll
    for (int ct = 0; ct < 4; ++ct)
#pragma unroll
      for (int kt = 0; kt < 4; ++kt) {
        lac[kt] = __builtin_amdgcn_mfma_f32_16x16x32_bf16(Ah[ct], wf[kt][ct][0], lac[kt], 0, 0, 0);
        lac[kt] = __builtin_amdgcn_mfma_f32_16x16x32_bf16(Al[ct], wf[kt][ct][0], lac[kt], 0, 0, 0);
        lac[kt] = __builtin_amdgcn_mfma_f32_16x16x32_bf16(Ah[ct], wf[kt][ct][1], lac[kt], 0, 0, 0);
      }
    // ---- in-register softmax: lane holds L[16kt+r][p0loc+4g+i] ----
    {
      f4 inv4 = *reinterpret_cast<const f4*>(&inv_lds[p0loc + 4 * g]);
      float lt[4][4];
#pragma unroll
      for (int kt = 0; kt < 4; ++kt)
#pragma unroll
        for (int i = 0; i < 4; ++i) lt[kt][i] = lac[kt][i] * inv4[i] + bb[kt];
      float mx[4], sm[4];
#pragma unroll
      for (int i = 0; i < 4; ++i)
        mx[i] = fmaxf(fmaxf(lt[0][i], lt[1][i]), fmaxf(lt[2][i], lt[3][i]));
#pragma unroll
      for (int o = 1; o <= 8; o <<= 1)
#pragma unroll
        for (int i = 0; i < 4; ++i) mx[i] = fmaxf(mx[i], __shfl_xor(mx[i], o));
#pragma unroll
      for (int i = 0; i < 4; ++i) sm[i] = 0.f;
#pragma unroll
      for (int kt = 0; kt < 4; ++kt)
#pragma unroll
        for (int i = 0; i < 4; ++i) {
          float e = __expf(lt[kt][i] - mx[i]);
          lt[kt][i] = e;
          sm[i] += e;
        }
#pragma unroll
      for (int o = 1; o <= 8; o <<= 1)
#pragma unroll
        for (int i = 0; i < 4; ++i) sm[i] += __shfl_xor(sm[i], o);
#pragma unroll
      for (int kt = 0; kt < 4; ++kt) {
        float av[4];
#pragma unroll
        for (int i = 0; i < 4; ++i) {
          float a = lt[kt][i] / sm[i];
          s_part[kt] += a;
          av[i] = a * inv4[i];
        }
        unsigned* arow = reinterpret_cast<unsigned*>(&a_lds[16 * kt + r][p0loc + 4 * g]);
        arow[0] = (unsigned)f2bf(av[0]) | ((unsigned)f2bf(av[1]) << 16);
        arow[1] = (unsigned)f2bf(av[2]) | ((unsigned)f2bf(av[3]) << 16);
      }
    }
    __syncthreads();
    // ---- vlad partial: wave owns k-tile wv x 128c, contract 64 p ----
#pragma unroll
    for (int pb = 0; pb < 2; ++pb) {
      bf16x8 af = *reinterpret_cast<const bf16x8*>(&a_lds[k0 + r][32 * pb + 8 * g]);
#pragma unroll
      for (int tcl = 0; tcl < 8; ++tcl) {
        const int c = (tcl << 4) + r;
        const int pblk = ((pb << 2) + g) ^ ((c >> 3) & 3);
        bf16x8 bx = *reinterpret_cast<const bf16x8*>(&xh[c][pblk << 3]);
        vacc[tcl] = __builtin_amdgcn_mfma_f32_16x16x32_bf16(af, bx, vacc[tcl], 0, 0, 0);
      }
    }
  }

  // ---- S reduction over g-groups, then atomics (lane r of g==0 holds S[16kt+r] partial) ----
#pragma unroll
  for (int kt = 0; kt < 4; ++kt) {
    float v = s_part[kt];
    v += __shfl_xor(v, 16);
    v += __shfl_xor(v, 32);
    if (g == 0) atomicAdd(&s_acc[n * NK + 16 * kt + r], v);
  }
  // ---- vlad atomics: D row k0+4g+i, col 16tcl+r ----
#pragma unroll
  for (int tcl = 0; tcl < 8; ++tcl)
#pragma unroll
    for (int i = 0; i < 4; ++i)
      atomicAdd(&vlad_acc[((size_t)n * NK + k0 + 4 * g + i) * NC + (tcl << 4) + r],
                vacc[tcl][i]);
}

// Per (n,k): subtract S*centroid, intra-normalize over C, accumulate global sumsq.
__global__ void nv_finalize(const float* __restrict__ vlad_acc,
                            const float* __restrict__ s_acc,
                            const float* __restrict__ centroids,
                            float* __restrict__ out, float* __restrict__ gnorm) {
  const int k = blockIdx.x;
  const int n = blockIdx.y;
  const int t = threadIdx.x;  // 64 threads
  const float s = s_acc[n * NK + k];
  const size_t base = ((size_t)n * NK + k) * NC;
  float v0 = vlad_acc[base + t] - s * centroids[k * NC + t];
  float v1 = vlad_acc[base + t + 64] - s * centroids[k * NC + t + 64];
  float ss = v0 * v0 + v1 * v1;
#pragma unroll
  for (int off = 1; off < 64; off <<= 1) ss += __shfl_xor(ss, off);
  float inv = 1.0f / fmaxf(sqrtf(ss), EPSV);
  out[base + t] = v0 * inv;
  out[base + t + 64] = v1 * inv;
  if (t == 0) atomicAdd(&gnorm[n], ss * inv * inv);
}

__global__ void nv_scale(float* __restrict__ out, const float* __restrict__ gnorm) {
  int i = blockIdx.x * blockDim.x + threadIdx.x;  // 262144 elements
  int n = i >> 13;
  out[i] *= 1.0f / fmaxf(sqrtf(gnorm[n]), EPSV);
}

extern "C" void kernel_launch(void* const* d_in, const int* in_sizes, int n_in,
                              void* d_out, int out_size, void* d_ws, size_t ws_size,
                              hipStream_t stream) {
  const float* x = (const float*)d_in[0];
  const float* conv_w = (const float*)d_in[1];
  const float* conv_b = (const float*)d_in[2];
  const float* centroids = (const float*)d_in[3];
  float* out = (float*)d_out;
  float* ws = (float*)d_ws;
  float* vlad_acc = ws + WS_VLAD;
  float* s_acc = ws + WS_S;
  float* gnorm = ws + WS_G;
  unsigned short* wfrag = (unsigned short*)(ws + WS_WF);

  nv_zero<<<256, 256, 0, stream>>>(ws);
  nv_wfrag<<<8, 256, 0, stream>>>(conv_w, wfrag);
  nv_main<<<dim3(NGRPX, NN), 256, 0, stream>>>(x, wfrag, conv_b, vlad_acc, s_acc);
  nv_finalize<<<dim3(NK, NN), 64, 0, stream>>>(vlad_acc, s_acc, centroids, out, gnorm);
  nv_scale<<<1024, 256, 0, stream>>>(out, gnorm);
}